// Round 1
// 671.862 us; speedup vs baseline: 1.8883x; 1.8883x over previous
//
#include <hip/hip_runtime.h>

#define DIM_D 128
#define DIM_2D 256
#define DIM_H 128
#define DIM_O 64

struct EdgeSW { int s; float w; };   // 8B packed, one dwordx2 per edge

typedef __attribute__((ext_vector_type(8))) short short8v;  // 8 bf16 (4 VGPRs)
typedef __attribute__((ext_vector_type(4))) float f32x4;    // 4 fp32 acc

// ---------------------------------------------------------------------------
// CSR build: histogram -> 3-kernel exclusive scan -> placement (unchanged)
// ---------------------------------------------------------------------------
__global__ __launch_bounds__(256) void hist_k(const int* __restrict__ dst,
                                              int* __restrict__ cnt, int E)
{
    int i = blockIdx.x * 256 + threadIdx.x;
    if (i < E) atomicAdd(&cnt[dst[i]], 1);
}

__global__ __launch_bounds__(256) void scan_reduce(const int* __restrict__ cnt,
                                                   int* __restrict__ bsum, int N)
{
    int b = blockIdx.x, t = threadIdx.x;
    int base = b * 1024 + t * 4;
    int s = 0;
    #pragma unroll
    for (int k = 0; k < 4; ++k) { int i = base + k; if (i < N) s += cnt[i]; }
    __shared__ int sh[256];
    sh[t] = s; __syncthreads();
    for (int off = 128; off > 0; off >>= 1) {
        if (t < off) sh[t] += sh[t + off];
        __syncthreads();
    }
    if (t == 0) bsum[b] = sh[0];
}

__global__ void scan_bsum(int* bsum, int NB)
{
    if (threadIdx.x == 0) {
        int run = 0;
        for (int i = 0; i < NB; ++i) { int v = bsum[i]; bsum[i] = run; run += v; }
    }
}

__global__ __launch_bounds__(256) void scan_write(const int* __restrict__ cnt,
                                                  const int* __restrict__ bsum,
                                                  int* __restrict__ starts, int N)
{
    int b = blockIdx.x, t = threadIdx.x;
    int base = b * 1024 + t * 4;
    int v[4]; int s = 0;
    #pragma unroll
    for (int k = 0; k < 4; ++k) { int i = base + k; v[k] = (i < N) ? cnt[i] : 0; s += v[k]; }
    __shared__ int sh[256];
    sh[t] = s; __syncthreads();
    for (int off = 1; off < 256; off <<= 1) {
        int x = 0;
        if (t >= off) x = sh[t - off];
        __syncthreads();
        if (t >= off) sh[t] += x;
        __syncthreads();
    }
    int run = bsum[b] + (t > 0 ? sh[t - 1] : 0);
    #pragma unroll
    for (int k = 0; k < 4; ++k) {
        int i = base + k;
        if (i < N) {
            starts[i] = run;
            run += v[k];
            if (i == N - 1) starts[N] = run;
        }
    }
}

__global__ __launch_bounds__(256) void place_k(const int* __restrict__ src,
                                               const int* __restrict__ dst,
                                               const float* __restrict__ ew,
                                               const int* __restrict__ starts,
                                               int* __restrict__ cur,
                                               EdgeSW* __restrict__ csr, int E)
{
    int i = blockIdx.x * 256 + threadIdx.x;
    if (i >= E) return;
    int d = dst[i];
    int pos = starts[d] + atomicAdd(&cur[d], 1);
    EdgeSW e; e.s = src[i]; e.w = ew[i];
    csr[pos] = e;
}

// ---------------------------------------------------------------------------
// Gather: one 64-lane wave per dst node; lane owns 2 columns. (unchanged)
// ---------------------------------------------------------------------------
__global__ __launch_bounds__(256) void gather_k(const EdgeSW* __restrict__ csr,
                                                const int* __restrict__ starts,
                                                const float* __restrict__ emb,
                                                float* __restrict__ msg, int N)
{
    int wv = (blockIdx.x * 256 + threadIdx.x) >> 6;
    int lane = threadIdx.x & 63;
    if (wv >= N) return;
    int s0 = starts[wv], s1 = starts[wv + 1];
    float ax = 0.f, ay = 0.f, degw = 0.f;
    int i = s0;
    for (; i + 4 <= s1; i += 4) {
        EdgeSW e0 = csr[i], e1 = csr[i + 1], e2 = csr[i + 2], e3 = csr[i + 3];
        float2 v0 = *reinterpret_cast<const float2*>(emb + (size_t)e0.s * DIM_D + lane * 2);
        float2 v1 = *reinterpret_cast<const float2*>(emb + (size_t)e1.s * DIM_D + lane * 2);
        float2 v2 = *reinterpret_cast<const float2*>(emb + (size_t)e2.s * DIM_D + lane * 2);
        float2 v3 = *reinterpret_cast<const float2*>(emb + (size_t)e3.s * DIM_D + lane * 2);
        ax += v0.x * e0.w + v1.x * e1.w + v2.x * e2.w + v3.x * e3.w;
        ay += v0.y * e0.w + v1.y * e1.w + v2.y * e2.w + v3.y * e3.w;
        degw += e0.w + e1.w + e2.w + e3.w;
    }
    for (; i < s1; ++i) {
        EdgeSW e0 = csr[i];
        float2 v0 = *reinterpret_cast<const float2*>(emb + (size_t)e0.s * DIM_D + lane * 2);
        ax += v0.x * e0.w;
        ay += v0.y * e0.w;
        degw += e0.w;
    }
    float inv = 1.0f / (degw + 1e-8f);
    *reinterpret_cast<float2*>(msg + (size_t)wv * DIM_D + lane * 2) =
        make_float2(ax * inv, ay * inv);
}

// ---------------------------------------------------------------------------
// Fused MLP via bf16x3 MFMA (x = hi + lo split; hi*hi + hi*lo + lo*hi).
// Block: 256 threads = 4 waves, 64 nodes. Wave w owns rows 16w..16w+15.
// K-permutation invariance: the same (group,elem)->k map is used for both
// MFMA operands, so correctness does not depend on the HW's A/B k-ordering.
// C/D layout (HW-verified): col = lane&15, row = (lane>>4)*4 + reg.
// LDS rows XOR-swizzled (byte ^= (row&7)<<4) to kill 16-way read conflicts.
// ---------------------------------------------------------------------------
#define XS_HI  0        // [64 ][64k] bf16 hi,  row stride 128B  (8 KiB)
#define XS_LO  8192     // [64 ][64k] bf16 lo                    (8 KiB)
#define W1S_HI 16384    // [128][64k] bf16 hi,  row stride 128B  (16 KiB)
#define W1S_LO 32768    // [128][64k] bf16 lo                    (16 KiB)
// phase-2 aliases (safe: first written after the last GEMM1 barrier)
#define YS_HI  0        // [64 ][128k] bf16 hi, row stride 256B  (16 KiB)
#define YS_LO  16384    // [64 ][128k] bf16 lo                   (16 KiB)
#define W2S_HI 32768    // [64 ][64k]  bf16 hi, row stride 128B  (8 KiB)
#define W2S_LO 40960    // [64 ][64k]  bf16 lo                   (8 KiB)
#define SMEM_BYTES 49152

__device__ __forceinline__ void split_bf(float x, unsigned short& hi, unsigned short& lo)
{
    union { float f; unsigned u; } v; v.f = x;
    hi = (unsigned short)(v.u >> 16);                 // truncate: lo compensates
    union { unsigned u; float f; } hv; hv.u = v.u & 0xFFFF0000u;
    union { float f; unsigned u; } rv; rv.f = x - hv.f;
    lo = (unsigned short)(rv.u >> 16);
}

__device__ __forceinline__ void stage_pair(char* hi_base, char* lo_base,
                                           int row, int rowbytes, int posB, float4 v)
{
    int byte = row * rowbytes + (posB ^ ((row & 7) << 4));
    unsigned short h0, h1, h2, h3, l0, l1, l2, l3;
    split_bf(v.x, h0, l0); split_bf(v.y, h1, l1);
    split_bf(v.z, h2, l2); split_bf(v.w, h3, l3);
    uint2 hp, lp;
    hp.x = (unsigned)h0 | ((unsigned)h1 << 16);
    hp.y = (unsigned)h2 | ((unsigned)h3 << 16);
    lp.x = (unsigned)l0 | ((unsigned)l1 << 16);
    lp.y = (unsigned)l2 | ((unsigned)l3 << 16);
    *reinterpret_cast<uint2*>(hi_base + byte) = hp;
    *reinterpret_cast<uint2*>(lo_base + byte) = lp;
}

__device__ __forceinline__ short8v ld_frag(const char* base, int row, int rowbytes, int posB)
{
    int byte = row * rowbytes + (posB ^ ((row & 7) << 4));
    return *reinterpret_cast<const short8v*>(base + byte);
}

__global__ __launch_bounds__(256, 3) void gnn_mlp(
    const float* __restrict__ emb, const float* __restrict__ msg,
    const float* __restrict__ W1, const float* __restrict__ b1,
    const float* __restrict__ g1, const float* __restrict__ be1,
    const float* __restrict__ W2, const float* __restrict__ b2,
    const float* __restrict__ g2, const float* __restrict__ be2,
    float* __restrict__ out, int N)
{
    __shared__ uint4 smem4[SMEM_BYTES / 16];
    char* smem = reinterpret_cast<char*>(smem4);

    const int t    = threadIdx.x;
    const int lane = t & 63;
    const int wv   = t >> 6;        // wave 0..3, owns rows 16wv..16wv+15
    const int l15  = lane & 15;
    const int g    = lane >> 4;     // k-group 0..3
    const int r0   = blockIdx.x * 64;

    f32x4 acc[8];
    #pragma unroll
    for (int nt = 0; nt < 8; ++nt)
        #pragma unroll
        for (int r = 0; r < 4; ++r) acc[nt][r] = 0.f;

    // ---------------- GEMM1: [64x256] x W1^T[256x128], K chunks of 64 -------
    for (int kc = 0; kc < 4; ++kc) {
        #pragma unroll
        for (int i = 0; i < 4; ++i) {           // stage X chunk (64x64 fp32)
            int lin = t + i * 256;
            int row = lin >> 4;
            int c4  = (lin & 15) << 2;
            int node = r0 + row;
            float4 v = make_float4(0.f, 0.f, 0.f, 0.f);
            if (node < N) {
                int col = kc * 64 + c4;
                v = (col < DIM_D)
                  ? *reinterpret_cast<const float4*>(emb + (size_t)node * DIM_D + col)
                  : *reinterpret_cast<const float4*>(msg + (size_t)node * DIM_D + (col - DIM_D));
            }
            stage_pair(smem + XS_HI, smem + XS_LO, row, 128, c4 * 2, v);
        }
        #pragma unroll
        for (int i = 0; i < 8; ++i) {           // stage W1 chunk (128x64 fp32)
            int lin = t + i * 256;
            int row = lin >> 4;
            int c4  = (lin & 15) << 2;
            float4 v = *reinterpret_cast<const float4*>(W1 + (size_t)row * DIM_2D + kc * 64 + c4);
            stage_pair(smem + W1S_HI, smem + W1S_LO, row, 128, c4 * 2, v);
        }
        __syncthreads();
        #pragma unroll
        for (int ks = 0; ks < 2; ++ks) {
            int pos = ks * 64 + g * 16;
            short8v a_hi = ld_frag(smem + XS_HI, wv * 16 + l15, 128, pos);
            short8v a_lo = ld_frag(smem + XS_LO, wv * 16 + l15, 128, pos);
            #pragma unroll
            for (int nt = 0; nt < 8; ++nt) {
                short8v b_hi = ld_frag(smem + W1S_HI, nt * 16 + l15, 128, pos);
                short8v b_lo = ld_frag(smem + W1S_LO, nt * 16 + l15, 128, pos);
                acc[nt] = __builtin_amdgcn_mfma_f32_16x16x32_bf16(a_hi, b_hi, acc[nt], 0, 0, 0);
                acc[nt] = __builtin_amdgcn_mfma_f32_16x16x32_bf16(a_hi, b_lo, acc[nt], 0, 0, 0);
                acc[nt] = __builtin_amdgcn_mfma_f32_16x16x32_bf16(a_lo, b_hi, acc[nt], 0, 0, 0);
            }
        }
        __syncthreads();
    }

    // ---------------- LN1 + relu (wave-local), write Y to LDS as bf16 pair --
    float b1v[8], g1v[8], be1v[8];
    #pragma unroll
    for (int nt = 0; nt < 8; ++nt) {
        int c = l15 + nt * 16;
        b1v[nt] = b1[c]; g1v[nt] = g1[c]; be1v[nt] = be1[c];
    }
    {
        float s[4] = {0.f, 0.f, 0.f, 0.f}, s2[4] = {0.f, 0.f, 0.f, 0.f};
        #pragma unroll
        for (int nt = 0; nt < 8; ++nt)
            #pragma unroll
            for (int r = 0; r < 4; ++r) {
                float v = acc[nt][r] + b1v[nt];
                acc[nt][r] = v;
                s[r] += v; s2[r] += v * v;
            }
        #pragma unroll
        for (int r = 0; r < 4; ++r) {
            #pragma unroll
            for (int d = 1; d < 16; d <<= 1) {
                s[r]  += __shfl_xor(s[r],  d);
                s2[r] += __shfl_xor(s2[r], d);
            }
            float mu  = s[r] * (1.f / 128.f);
            float var = s2[r] * (1.f / 128.f) - mu * mu;
            float inv = rsqrtf(var + 1e-5f);
            int row = wv * 16 + g * 4 + r;
            #pragma unroll
            for (int nt = 0; nt < 8; ++nt) {
                float h = fmaxf((acc[nt][r] - mu) * inv * g1v[nt] + be1v[nt], 0.f);
                unsigned short hh, hl;
                split_bf(h, hh, hl);
                int k = l15 + nt * 16;
                int byte = row * 256 + ((k * 2) ^ ((row & 7) << 4));
                *reinterpret_cast<unsigned short*>(smem + YS_HI + byte) = hh;
                *reinterpret_cast<unsigned short*>(smem + YS_LO + byte) = hl;
            }
        }
    }

    // ---------------- GEMM2: Y[64x128] x W2^T[128x64], K chunks of 64 -------
    auto stageW2 = [&](int kc2) {
        #pragma unroll
        for (int i = 0; i < 4; ++i) {
            int lin = t + i * 256;
            int row = lin >> 4;
            int c4  = (lin & 15) << 2;
            float4 v = *reinterpret_cast<const float4*>(W2 + (size_t)row * DIM_H + kc2 * 64 + c4);
            stage_pair(smem + W2S_HI, smem + W2S_LO, row, 128, c4 * 2, v);
        }
    };
    stageW2(0);
    __syncthreads();

    f32x4 acc2[4];
    #pragma unroll
    for (int nt = 0; nt < 4; ++nt)
        #pragma unroll
        for (int r = 0; r < 4; ++r) acc2[nt][r] = 0.f;

    for (int kc2 = 0; kc2 < 2; ++kc2) {
        if (kc2) { __syncthreads(); stageW2(1); __syncthreads(); }
        #pragma unroll
        for (int ks2 = 0; ks2 < 2; ++ks2) {
            int posY = (kc2 * 2 + ks2) * 64 + g * 16;
            int posW = ks2 * 64 + g * 16;
            short8v a_hi = ld_frag(smem + YS_HI, wv * 16 + l15, 256, posY);
            short8v a_lo = ld_frag(smem + YS_LO, wv * 16 + l15, 256, posY);
            #pragma unroll
            for (int nt = 0; nt < 4; ++nt) {
                short8v b_hi = ld_frag(smem + W2S_HI, nt * 16 + l15, 128, posW);
                short8v b_lo = ld_frag(smem + W2S_LO, nt * 16 + l15, 128, posW);
                acc2[nt] = __builtin_amdgcn_mfma_f32_16x16x32_bf16(a_hi, b_hi, acc2[nt], 0, 0, 0);
                acc2[nt] = __builtin_amdgcn_mfma_f32_16x16x32_bf16(a_hi, b_lo, acc2[nt], 0, 0, 0);
                acc2[nt] = __builtin_amdgcn_mfma_f32_16x16x32_bf16(a_lo, b_hi, acc2[nt], 0, 0, 0);
            }
        }
    }

    // ---------------- LN2 (wave-local) + store --------------------------------
    float b2v[4], g2v[4], be2v[4];
    #pragma unroll
    for (int nt = 0; nt < 4; ++nt) {
        int c = l15 + nt * 16;
        b2v[nt] = b2[c]; g2v[nt] = g2[c]; be2v[nt] = be2[c];
    }
    #pragma unroll
    for (int r = 0; r < 4; ++r) {
        float vv[4];
        float ss = 0.f, ss2 = 0.f;
        #pragma unroll
        for (int nt = 0; nt < 4; ++nt) {
            float v = acc2[nt][r] + b2v[nt];
            vv[nt] = v; ss += v; ss2 += v * v;
        }
        #pragma unroll
        for (int d = 1; d < 16; d <<= 1) {
            ss  += __shfl_xor(ss,  d);
            ss2 += __shfl_xor(ss2, d);
        }
        float mu  = ss * (1.f / 64.f);
        float var = ss2 * (1.f / 64.f) - mu * mu;
        float inv = rsqrtf(var + 1e-5f);
        int node = r0 + wv * 16 + g * 4 + r;
        if (node < N) {
            #pragma unroll
            for (int nt = 0; nt < 4; ++nt)
                out[(size_t)node * DIM_O + l15 + nt * 16] = (vv[nt] - mu) * inv * g2v[nt] + be2v[nt];
        }
    }
}

extern "C" void kernel_launch(void* const* d_in, const int* in_sizes, int n_in,
                              void* d_out, int out_size, void* d_ws, size_t ws_size,
                              hipStream_t stream)
{
    const int*   pc_edges = (const int*)d_in[0];   // provider->code (2,E): src=provider, dst=code
    const int*   cp_edges = (const int*)d_in[1];   // code->provider (2,E): src=code, dst=provider
    const float* ew       = (const float*)d_in[2];
    const float* p_emb    = (const float*)d_in[3];
    const float* c_emb    = (const float*)d_in[4];
    const float* p_W1  = (const float*)d_in[5];
    const float* p_b1  = (const float*)d_in[6];
    const float* p_g1  = (const float*)d_in[7];
    const float* p_be1 = (const float*)d_in[8];
    const float* p_W2  = (const float*)d_in[9];
    const float* p_b2  = (const float*)d_in[10];
    const float* p_g2  = (const float*)d_in[11];
    const float* p_be2 = (const float*)d_in[12];
    const float* c_W1  = (const float*)d_in[13];
    const float* c_b1  = (const float*)d_in[14];
    const float* c_g1  = (const float*)d_in[15];
    const float* c_be1 = (const float*)d_in[16];
    const float* c_W2  = (const float*)d_in[17];
    const float* c_b2  = (const float*)d_in[18];
    const float* c_g2  = (const float*)d_in[19];
    const float* c_be2 = (const float*)d_in[20];

    const int E  = in_sizes[2];
    const int NP = in_sizes[3] / DIM_D;
    const int NC = in_sizes[4] / DIM_D;

    // workspace layout
    char* ws = (char*)d_ws;
    size_t off = 0;
    float*  prov_msg = (float*)(ws + off); off += (size_t)NP * DIM_D * sizeof(float);
    float*  code_msg = (float*)(ws + off); off += (size_t)NC * DIM_D * sizeof(float);
    EdgeSW* csr_cp   = (EdgeSW*)(ws + off); off += (size_t)E * sizeof(EdgeSW);
    EdgeSW* csr_pc   = (EdgeSW*)(ws + off); off += (size_t)E * sizeof(EdgeSW);
    int* starts_p = (int*)(ws + off); off += (size_t)(NP + 1) * sizeof(int);
    int* cnt_p    = (int*)(ws + off); off += (size_t)NP * sizeof(int);
    int* starts_c = (int*)(ws + off); off += (size_t)(NC + 1) * sizeof(int);
    int* cnt_c    = (int*)(ws + off); off += (size_t)NC * sizeof(int);
    int* bsum     = (int*)(ws + off); off += 256 * sizeof(int);
    (void)ws_size;

    const int EB  = (E + 255) / 256;
    const int NBp = (NP + 1023) / 1024;
    const int NBc = (NC + 1023) / 1024;

    // ---- code -> provider direction (src indexes code_emb, dst is provider)
    hipMemsetAsync(cnt_p, 0, (size_t)NP * sizeof(int), stream);
    hist_k<<<EB, 256, 0, stream>>>(cp_edges + E, cnt_p, E);
    scan_reduce<<<NBp, 256, 0, stream>>>(cnt_p, bsum, NP);
    scan_bsum<<<1, 64, 0, stream>>>(bsum, NBp);
    scan_write<<<NBp, 256, 0, stream>>>(cnt_p, bsum, starts_p, NP);
    hipMemsetAsync(cnt_p, 0, (size_t)NP * sizeof(int), stream);
    place_k<<<EB, 256, 0, stream>>>(cp_edges, cp_edges + E, ew, starts_p, cnt_p, csr_cp, E);
    gather_k<<<(NP + 3) / 4, 256, 0, stream>>>(csr_cp, starts_p, c_emb, prov_msg, NP);

    // ---- provider -> code direction
    hipMemsetAsync(cnt_c, 0, (size_t)NC * sizeof(int), stream);
    hist_k<<<EB, 256, 0, stream>>>(pc_edges + E, cnt_c, E);
    scan_reduce<<<NBc, 256, 0, stream>>>(cnt_c, bsum, NC);
    scan_bsum<<<1, 64, 0, stream>>>(bsum, NBc);
    scan_write<<<NBc, 256, 0, stream>>>(cnt_c, bsum, starts_c, NC);
    hipMemsetAsync(cnt_c, 0, (size_t)NC * sizeof(int), stream);
    place_k<<<EB, 256, 0, stream>>>(pc_edges, pc_edges + E, ew, starts_c, cnt_c, csr_pc, E);
    gather_k<<<(NC + 3) / 4, 256, 0, stream>>>(csr_pc, starts_c, p_emb, code_msg, NC);

    // ---- MLPs (bf16x3 MFMA)
    float* out = (float*)d_out;
    gnn_mlp<<<(NP + 63) / 64, 256, 0, stream>>>(p_emb, prov_msg,
        p_W1, p_b1, p_g1, p_be1, p_W2, p_b2, p_g2, p_be2, out, NP);
    gnn_mlp<<<(NC + 63) / 64, 256, 0, stream>>>(c_emb, code_msg,
        c_W1, c_b1, c_g1, c_be1, c_W2, c_b2, c_g2, c_be2,
        out + (size_t)NP * DIM_O, NC);
}

// Round 2
// 596.735 us; speedup vs baseline: 2.1261x; 1.1259x over previous
//
#include <hip/hip_runtime.h>

#define DIM_D 128
#define DIM_2D 256
#define DIM_H 128
#define DIM_O 64

struct EdgeSW { int s; float w; };   // 8B packed

typedef __attribute__((ext_vector_type(8))) short short8v;  // 8 bf16 (4 VGPRs)
typedef __attribute__((ext_vector_type(4))) float f32x4;    // 4 fp32 acc

__device__ __forceinline__ EdgeSW ld_edge_nt(const EdgeSW* p)
{
    unsigned long long v =
        __builtin_nontemporal_load(reinterpret_cast<const unsigned long long*>(p));
    EdgeSW e;
    e.s = (int)(unsigned)(v & 0xFFFFFFFFull);
    union { unsigned u; float f; } w; w.u = (unsigned)(v >> 32); e.w = w.f;
    return e;
}

// ---------------------------------------------------------------------------
// CSR build, both directions fused per stage.
// ---------------------------------------------------------------------------
__global__ __launch_bounds__(256) void hist_both(
    const int* __restrict__ cp_dst, int* __restrict__ cnt_p,
    const int* __restrict__ pc_dst, int* __restrict__ cnt_c,
    int E, int EB)
{
    int b = blockIdx.x;
    const int* dst; int* cnt;
    if (b < EB) { dst = cp_dst; cnt = cnt_p; }
    else        { dst = pc_dst; cnt = cnt_c; b -= EB; }
    int i = b * 256 + threadIdx.x;
    if (i < E) atomicAdd(&cnt[dst[i]], 1);
}

__global__ __launch_bounds__(256) void scan_reduce_both(
    const int* __restrict__ cnt_p, int* __restrict__ bsum_p, int NP, int NBp,
    const int* __restrict__ cnt_c, int* __restrict__ bsum_c, int NC)
{
    int b = blockIdx.x, t = threadIdx.x;
    const int* cnt; int* bsum; int N;
    if (b < NBp) { cnt = cnt_p; bsum = bsum_p; N = NP; }
    else         { cnt = cnt_c; bsum = bsum_c; N = NC; b -= NBp; }
    int base = b * 1024 + t * 4;
    int s = 0;
    #pragma unroll
    for (int k = 0; k < 4; ++k) { int i = base + k; if (i < N) s += cnt[i]; }
    __shared__ int sh[256];
    sh[t] = s; __syncthreads();
    for (int off = 128; off > 0; off >>= 1) {
        if (t < off) sh[t] += sh[t + off];
        __syncthreads();
    }
    if (t == 0) bsum[b] = sh[0];
}

// computes its own bsum prefix (<=98 elements), writes starts, zeros cnt (-> cur)
__global__ __launch_bounds__(256) void scan_write_both(
    int* __restrict__ cnt_p, const int* __restrict__ bsum_p,
    int* __restrict__ starts_p, int NP, int NBp,
    int* __restrict__ cnt_c, const int* __restrict__ bsum_c,
    int* __restrict__ starts_c, int NC)
{
    int b = blockIdx.x, t = threadIdx.x;
    int* cnt; const int* bsum; int* starts; int N;
    if (b < NBp) { cnt = cnt_p; bsum = bsum_p; starts = starts_p; N = NP; }
    else         { cnt = cnt_c; bsum = bsum_c; starts = starts_c; N = NC; b -= NBp; }

    __shared__ int base0;
    if (t == 0) {
        int r = 0;
        for (int j = 0; j < b; ++j) r += bsum[j];
        base0 = r;
    }

    int base = b * 1024 + t * 4;
    int v[4]; int s = 0;
    #pragma unroll
    for (int k = 0; k < 4; ++k) { int i = base + k; v[k] = (i < N) ? cnt[i] : 0; s += v[k]; }
    __shared__ int sh[256];
    sh[t] = s; __syncthreads();
    for (int off = 1; off < 256; off <<= 1) {
        int x = 0;
        if (t >= off) x = sh[t - off];
        __syncthreads();
        if (t >= off) sh[t] += x;
        __syncthreads();
    }
    int run = base0 + (t > 0 ? sh[t - 1] : 0);
    #pragma unroll
    for (int k = 0; k < 4; ++k) {
        int i = base + k;
        if (i < N) {
            starts[i] = run;
            run += v[k];
            cnt[i] = 0;                    // reset -> reused as cursor in place
            if (i == N - 1) starts[N] = run;
        }
    }
}

__global__ __launch_bounds__(256) void place_both(
    const int* __restrict__ cp_edges, const int* __restrict__ starts_p,
    int* __restrict__ cur_p, EdgeSW* __restrict__ csr_cp,
    const int* __restrict__ pc_edges, const int* __restrict__ starts_c,
    int* __restrict__ cur_c, EdgeSW* __restrict__ csr_pc,
    const float* __restrict__ ew, int E, int EB)
{
    int b = blockIdx.x;
    const int* src; const int* dst; const int* starts; int* cur; EdgeSW* csr;
    if (b < EB) { src = cp_edges; dst = cp_edges + E; starts = starts_p; cur = cur_p; csr = csr_cp; }
    else        { src = pc_edges; dst = pc_edges + E; starts = starts_c; cur = cur_c; csr = csr_pc; b -= EB; }
    int i = b * 256 + threadIdx.x;
    if (i >= E) return;
    int d = dst[i];
    int pos = starts[d] + atomicAdd(&cur[d], 1);
    EdgeSW e; e.s = src[i]; e.w = ew[i];
    csr[pos] = e;
}

// ---------------------------------------------------------------------------
// Gather, both directions in one launch. Wave per node; 32 lanes cover a row
// (float4/lane), two edges processed concurrently across wave halves.
// ---------------------------------------------------------------------------
__global__ __launch_bounds__(256) void gather_both(
    const EdgeSW* __restrict__ csr_cp, const int* __restrict__ starts_p,
    const float* __restrict__ c_emb, float* __restrict__ prov_msg, int NP,
    const EdgeSW* __restrict__ csr_pc, const int* __restrict__ starts_c,
    const float* __restrict__ p_emb, float* __restrict__ code_msg, int NC)
{
    int wv = (blockIdx.x * 256 + threadIdx.x) >> 6;
    int lane = threadIdx.x & 63;
    const EdgeSW* csr; const int* starts; const float* emb; float* msg; int n;
    if (wv < NP)           { csr = csr_cp; starts = starts_p; emb = c_emb; msg = prov_msg; n = wv; }
    else if (wv < NP + NC) { csr = csr_pc; starts = starts_c; emb = p_emb; msg = code_msg; n = wv - NP; }
    else return;

    const int sub = lane >> 5;          // edge slot within pair
    const int c4  = (lane & 31) * 4;    // column base (float4)

    int s0 = starts[n], s1 = starts[n + 1];
    float4 acc = make_float4(0.f, 0.f, 0.f, 0.f);
    float degw = 0.f;
    int i = s0;
    for (; i + 8 <= s1; i += 8) {
        EdgeSW e0 = ld_edge_nt(csr + i + sub);
        EdgeSW e1 = ld_edge_nt(csr + i + 2 + sub);
        EdgeSW e2 = ld_edge_nt(csr + i + 4 + sub);
        EdgeSW e3 = ld_edge_nt(csr + i + 6 + sub);
        float4 v0 = *reinterpret_cast<const float4*>(emb + (size_t)e0.s * DIM_D + c4);
        float4 v1 = *reinterpret_cast<const float4*>(emb + (size_t)e1.s * DIM_D + c4);
        float4 v2 = *reinterpret_cast<const float4*>(emb + (size_t)e2.s * DIM_D + c4);
        float4 v3 = *reinterpret_cast<const float4*>(emb + (size_t)e3.s * DIM_D + c4);
        acc.x += v0.x * e0.w + v1.x * e1.w + v2.x * e2.w + v3.x * e3.w;
        acc.y += v0.y * e0.w + v1.y * e1.w + v2.y * e2.w + v3.y * e3.w;
        acc.z += v0.z * e0.w + v1.z * e1.w + v2.z * e2.w + v3.z * e3.w;
        acc.w += v0.w * e0.w + v1.w * e1.w + v2.w * e2.w + v3.w * e3.w;
        degw += e0.w + e1.w + e2.w + e3.w;
    }
    for (; i < s1; i += 2) {
        int idx = i + sub;
        if (idx < s1) {
            EdgeSW e0 = ld_edge_nt(csr + idx);
            float4 v0 = *reinterpret_cast<const float4*>(emb + (size_t)e0.s * DIM_D + c4);
            acc.x += v0.x * e0.w; acc.y += v0.y * e0.w;
            acc.z += v0.z * e0.w; acc.w += v0.w * e0.w;
            degw += e0.w;
        }
    }
    degw  += __shfl_xor(degw, 32);
    acc.x += __shfl_xor(acc.x, 32);
    acc.y += __shfl_xor(acc.y, 32);
    acc.z += __shfl_xor(acc.z, 32);
    acc.w += __shfl_xor(acc.w, 32);
    float inv = 1.0f / (degw + 1e-8f);
    if (lane < 32)
        *reinterpret_cast<float4*>(msg + (size_t)n * DIM_D + c4) =
            make_float4(acc.x * inv, acc.y * inv, acc.z * inv, acc.w * inv);
}

// ---------------------------------------------------------------------------
// Fused MLP via bf16x3 MFMA (unchanged math), both node types in one launch.
// ---------------------------------------------------------------------------
#define XS_HI  0
#define XS_LO  8192
#define W1S_HI 16384
#define W1S_LO 32768
#define YS_HI  0
#define YS_LO  16384
#define W2S_HI 32768
#define W2S_LO 40960
#define SMEM_BYTES 49152

__device__ __forceinline__ void split_bf(float x, unsigned short& hi, unsigned short& lo)
{
    union { float f; unsigned u; } v; v.f = x;
    hi = (unsigned short)(v.u >> 16);
    union { unsigned u; float f; } hv; hv.u = v.u & 0xFFFF0000u;
    union { float f; unsigned u; } rv; rv.f = x - hv.f;
    lo = (unsigned short)(rv.u >> 16);
}

__device__ __forceinline__ void stage_pair(char* hi_base, char* lo_base,
                                           int row, int rowbytes, int posB, float4 v)
{
    int byte = row * rowbytes + (posB ^ ((row & 7) << 4));
    unsigned short h0, h1, h2, h3, l0, l1, l2, l3;
    split_bf(v.x, h0, l0); split_bf(v.y, h1, l1);
    split_bf(v.z, h2, l2); split_bf(v.w, h3, l3);
    uint2 hp, lp;
    hp.x = (unsigned)h0 | ((unsigned)h1 << 16);
    hp.y = (unsigned)h2 | ((unsigned)h3 << 16);
    lp.x = (unsigned)l0 | ((unsigned)l1 << 16);
    lp.y = (unsigned)l2 | ((unsigned)l3 << 16);
    *reinterpret_cast<uint2*>(hi_base + byte) = hp;
    *reinterpret_cast<uint2*>(lo_base + byte) = lp;
}

__device__ __forceinline__ short8v ld_frag(const char* base, int row, int rowbytes, int posB)
{
    int byte = row * rowbytes + (posB ^ ((row & 7) << 4));
    return *reinterpret_cast<const short8v*>(base + byte);
}

__device__ __forceinline__ void mlp_body(int blk,
    const float* __restrict__ emb, const float* __restrict__ msg,
    const float* __restrict__ W1, const float* __restrict__ b1,
    const float* __restrict__ g1, const float* __restrict__ be1,
    const float* __restrict__ W2, const float* __restrict__ b2,
    const float* __restrict__ g2, const float* __restrict__ be2,
    float* __restrict__ out, int N)
{
    __shared__ uint4 smem4[SMEM_BYTES / 16];
    char* smem = reinterpret_cast<char*>(smem4);

    const int t    = threadIdx.x;
    const int lane = t & 63;
    const int wv   = t >> 6;
    const int l15  = lane & 15;
    const int g    = lane >> 4;
    const int r0   = blk * 64;

    f32x4 acc[8];
    #pragma unroll
    for (int nt = 0; nt < 8; ++nt)
        #pragma unroll
        for (int r = 0; r < 4; ++r) acc[nt][r] = 0.f;

    for (int kc = 0; kc < 4; ++kc) {
        #pragma unroll
        for (int i = 0; i < 4; ++i) {
            int lin = t + i * 256;
            int row = lin >> 4;
            int c4  = (lin & 15) << 2;
            int node = r0 + row;
            float4 v = make_float4(0.f, 0.f, 0.f, 0.f);
            if (node < N) {
                int col = kc * 64 + c4;
                v = (col < DIM_D)
                  ? *reinterpret_cast<const float4*>(emb + (size_t)node * DIM_D + col)
                  : *reinterpret_cast<const float4*>(msg + (size_t)node * DIM_D + (col - DIM_D));
            }
            stage_pair(smem + XS_HI, smem + XS_LO, row, 128, c4 * 2, v);
        }
        #pragma unroll
        for (int i = 0; i < 8; ++i) {
            int lin = t + i * 256;
            int row = lin >> 4;
            int c4  = (lin & 15) << 2;
            float4 v = *reinterpret_cast<const float4*>(W1 + (size_t)row * DIM_2D + kc * 64 + c4);
            stage_pair(smem + W1S_HI, smem + W1S_LO, row, 128, c4 * 2, v);
        }
        __syncthreads();
        #pragma unroll
        for (int ks = 0; ks < 2; ++ks) {
            int pos = ks * 64 + g * 16;
            short8v a_hi = ld_frag(smem + XS_HI, wv * 16 + l15, 128, pos);
            short8v a_lo = ld_frag(smem + XS_LO, wv * 16 + l15, 128, pos);
            #pragma unroll
            for (int nt = 0; nt < 8; ++nt) {
                short8v b_hi = ld_frag(smem + W1S_HI, nt * 16 + l15, 128, pos);
                short8v b_lo = ld_frag(smem + W1S_LO, nt * 16 + l15, 128, pos);
                acc[nt] = __builtin_amdgcn_mfma_f32_16x16x32_bf16(a_hi, b_hi, acc[nt], 0, 0, 0);
                acc[nt] = __builtin_amdgcn_mfma_f32_16x16x32_bf16(a_hi, b_lo, acc[nt], 0, 0, 0);
                acc[nt] = __builtin_amdgcn_mfma_f32_16x16x32_bf16(a_lo, b_hi, acc[nt], 0, 0, 0);
            }
        }
        __syncthreads();
    }

    float b1v[8], g1v[8], be1v[8];
    #pragma unroll
    for (int nt = 0; nt < 8; ++nt) {
        int c = l15 + nt * 16;
        b1v[nt] = b1[c]; g1v[nt] = g1[c]; be1v[nt] = be1[c];
    }
    {
        float s[4] = {0.f, 0.f, 0.f, 0.f}, s2[4] = {0.f, 0.f, 0.f, 0.f};
        #pragma unroll
        for (int nt = 0; nt < 8; ++nt)
            #pragma unroll
            for (int r = 0; r < 4; ++r) {
                float v = acc[nt][r] + b1v[nt];
                acc[nt][r] = v;
                s[r] += v; s2[r] += v * v;
            }
        #pragma unroll
        for (int r = 0; r < 4; ++r) {
            #pragma unroll
            for (int d = 1; d < 16; d <<= 1) {
                s[r]  += __shfl_xor(s[r],  d);
                s2[r] += __shfl_xor(s2[r], d);
            }
            float mu  = s[r] * (1.f / 128.f);
            float var = s2[r] * (1.f / 128.f) - mu * mu;
            float inv = rsqrtf(var + 1e-5f);
            int row = wv * 16 + g * 4 + r;
            #pragma unroll
            for (int nt = 0; nt < 8; ++nt) {
                float h = fmaxf((acc[nt][r] - mu) * inv * g1v[nt] + be1v[nt], 0.f);
                unsigned short hh, hl;
                split_bf(h, hh, hl);
                int k = l15 + nt * 16;
                int byte = row * 256 + ((k * 2) ^ ((row & 7) << 4));
                *reinterpret_cast<unsigned short*>(smem + YS_HI + byte) = hh;
                *reinterpret_cast<unsigned short*>(smem + YS_LO + byte) = hl;
            }
        }
    }

    auto stageW2 = [&](int kc2) {
        #pragma unroll
        for (int i = 0; i < 4; ++i) {
            int lin = t + i * 256;
            int row = lin >> 4;
            int c4  = (lin & 15) << 2;
            float4 v = *reinterpret_cast<const float4*>(W2 + (size_t)row * DIM_H + kc2 * 64 + c4);
            stage_pair(smem + W2S_HI, smem + W2S_LO, row, 128, c4 * 2, v);
        }
    };
    stageW2(0);
    __syncthreads();

    f32x4 acc2[4];
    #pragma unroll
    for (int nt = 0; nt < 4; ++nt)
        #pragma unroll
        for (int r = 0; r < 4; ++r) acc2[nt][r] = 0.f;

    for (int kc2 = 0; kc2 < 2; ++kc2) {
        if (kc2) { __syncthreads(); stageW2(1); __syncthreads(); }
        #pragma unroll
        for (int ks2 = 0; ks2 < 2; ++ks2) {
            int posY = (kc2 * 2 + ks2) * 64 + g * 16;
            int posW = ks2 * 64 + g * 16;
            short8v a_hi = ld_frag(smem + YS_HI, wv * 16 + l15, 256, posY);
            short8v a_lo = ld_frag(smem + YS_LO, wv * 16 + l15, 256, posY);
            #pragma unroll
            for (int nt = 0; nt < 4; ++nt) {
                short8v b_hi = ld_frag(smem + W2S_HI, nt * 16 + l15, 128, posW);
                short8v b_lo = ld_frag(smem + W2S_LO, nt * 16 + l15, 128, posW);
                acc2[nt] = __builtin_amdgcn_mfma_f32_16x16x32_bf16(a_hi, b_hi, acc2[nt], 0, 0, 0);
                acc2[nt] = __builtin_amdgcn_mfma_f32_16x16x32_bf16(a_hi, b_lo, acc2[nt], 0, 0, 0);
                acc2[nt] = __builtin_amdgcn_mfma_f32_16x16x32_bf16(a_lo, b_hi, acc2[nt], 0, 0, 0);
            }
        }
    }

    float b2v[4], g2v[4], be2v[4];
    #pragma unroll
    for (int nt = 0; nt < 4; ++nt) {
        int c = l15 + nt * 16;
        b2v[nt] = b2[c]; g2v[nt] = g2[c]; be2v[nt] = be2[c];
    }
    #pragma unroll
    for (int r = 0; r < 4; ++r) {
        float vv[4];
        float ss = 0.f, ss2 = 0.f;
        #pragma unroll
        for (int nt = 0; nt < 4; ++nt) {
            float v = acc2[nt][r] + b2v[nt];
            vv[nt] = v; ss += v; ss2 += v * v;
        }
        #pragma unroll
        for (int d = 1; d < 16; d <<= 1) {
            ss  += __shfl_xor(ss,  d);
            ss2 += __shfl_xor(ss2, d);
        }
        float mu  = ss * (1.f / 64.f);
        float var = ss2 * (1.f / 64.f) - mu * mu;
        float inv = rsqrtf(var + 1e-5f);
        int node = r0 + wv * 16 + g * 4 + r;
        if (node < N) {
            #pragma unroll
            for (int nt = 0; nt < 4; ++nt)
                out[(size_t)node * DIM_O + l15 + nt * 16] = (vv[nt] - mu) * inv * g2v[nt] + be2v[nt];
        }
    }
}

__global__ __launch_bounds__(256, 3) void gnn_mlp_both(
    const float* __restrict__ p_emb, const float* __restrict__ prov_msg,
    const float* __restrict__ p_W1, const float* __restrict__ p_b1,
    const float* __restrict__ p_g1, const float* __restrict__ p_be1,
    const float* __restrict__ p_W2, const float* __restrict__ p_b2,
    const float* __restrict__ p_g2, const float* __restrict__ p_be2,
    const float* __restrict__ c_emb, const float* __restrict__ code_msg,
    const float* __restrict__ c_W1, const float* __restrict__ c_b1,
    const float* __restrict__ c_g1, const float* __restrict__ c_be1,
    const float* __restrict__ c_W2, const float* __restrict__ c_b2,
    const float* __restrict__ c_g2, const float* __restrict__ c_be2,
    float* __restrict__ out, int NP, int NC, int NPB)
{
    if ((int)blockIdx.x < NPB) {
        mlp_body(blockIdx.x, p_emb, prov_msg,
                 p_W1, p_b1, p_g1, p_be1, p_W2, p_b2, p_g2, p_be2, out, NP);
    } else {
        mlp_body(blockIdx.x - NPB, c_emb, code_msg,
                 c_W1, c_b1, c_g1, c_be1, c_W2, c_b2, c_g2, c_be2,
                 out + (size_t)NP * DIM_O, NC);
    }
}

extern "C" void kernel_launch(void* const* d_in, const int* in_sizes, int n_in,
                              void* d_out, int out_size, void* d_ws, size_t ws_size,
                              hipStream_t stream)
{
    const int*   pc_edges = (const int*)d_in[0];   // provider->code (2,E)
    const int*   cp_edges = (const int*)d_in[1];   // code->provider (2,E)
    const float* ew       = (const float*)d_in[2];
    const float* p_emb    = (const float*)d_in[3];
    const float* c_emb    = (const float*)d_in[4];
    const float* p_W1  = (const float*)d_in[5];
    const float* p_b1  = (const float*)d_in[6];
    const float* p_g1  = (const float*)d_in[7];
    const float* p_be1 = (const float*)d_in[8];
    const float* p_W2  = (const float*)d_in[9];
    const float* p_b2  = (const float*)d_in[10];
    const float* p_g2  = (const float*)d_in[11];
    const float* p_be2 = (const float*)d_in[12];
    const float* c_W1  = (const float*)d_in[13];
    const float* c_b1  = (const float*)d_in[14];
    const float* c_g1  = (const float*)d_in[15];
    const float* c_be1 = (const float*)d_in[16];
    const float* c_W2  = (const float*)d_in[17];
    const float* c_b2  = (const float*)d_in[18];
    const float* c_g2  = (const float*)d_in[19];
    const float* c_be2 = (const float*)d_in[20];

    const int E  = in_sizes[2];
    const int NP = in_sizes[3] / DIM_D;
    const int NC = in_sizes[4] / DIM_D;

    // workspace layout (cnt_p/cnt_c contiguous for a single memset)
    char* ws = (char*)d_ws;
    size_t off = 0;
    float*  prov_msg = (float*)(ws + off); off += (size_t)NP * DIM_D * sizeof(float);
    float*  code_msg = (float*)(ws + off); off += (size_t)NC * DIM_D * sizeof(float);
    EdgeSW* csr_cp   = (EdgeSW*)(ws + off); off += (size_t)E * sizeof(EdgeSW);
    EdgeSW* csr_pc   = (EdgeSW*)(ws + off); off += (size_t)E * sizeof(EdgeSW);
    int* starts_p = (int*)(ws + off); off += (size_t)(NP + 1) * sizeof(int);
    int* starts_c = (int*)(ws + off); off += (size_t)(NC + 1) * sizeof(int);
    int* cnt_p    = (int*)(ws + off); off += (size_t)NP * sizeof(int);
    int* cnt_c    = (int*)(ws + off); off += (size_t)NC * sizeof(int);
    int* bsum_p   = (int*)(ws + off); off += 256 * sizeof(int);
    int* bsum_c   = (int*)(ws + off); off += 256 * sizeof(int);
    (void)ws_size;

    const int EB  = (E + 255) / 256;
    const int NBp = (NP + 1023) / 1024;
    const int NBc = (NC + 1023) / 1024;
    const int NPB = (NP + 63) / 64;
    const int NCB = (NC + 63) / 64;

    hipMemsetAsync(cnt_p, 0, (size_t)(NP + NC) * sizeof(int), stream);

    hist_both<<<2 * EB, 256, 0, stream>>>(cp_edges + E, cnt_p, pc_edges + E, cnt_c, E, EB);

    scan_reduce_both<<<NBp + NBc, 256, 0, stream>>>(cnt_p, bsum_p, NP, NBp,
                                                    cnt_c, bsum_c, NC);

    scan_write_both<<<NBp + NBc, 256, 0, stream>>>(cnt_p, bsum_p, starts_p, NP, NBp,
                                                   cnt_c, bsum_c, starts_c, NC);

    place_both<<<2 * EB, 256, 0, stream>>>(cp_edges, starts_p, cnt_p, csr_cp,
                                           pc_edges, starts_c, cnt_c, csr_pc,
                                           ew, E, EB);

    gather_both<<<(NP + NC + 3) / 4, 256, 0, stream>>>(
        csr_cp, starts_p, c_emb, prov_msg, NP,
        csr_pc, starts_c, p_emb, code_msg, NC);

    gnn_mlp_both<<<NPB + NCB, 256, 0, stream>>>(
        p_emb, prov_msg, p_W1, p_b1, p_g1, p_be1, p_W2, p_b2, p_g2, p_be2,
        c_emb, code_msg, c_W1, c_b1, c_g1, c_be1, c_W2, c_b2, c_g2, c_be2,
        (float*)d_out, NP, NC, NPB);
}